// Round 1
// baseline (83.806 us; speedup 1.0000x reference)
//
#include <hip/hip_runtime.h>

#define GROUPS 196
#define NUM_BINS 4

__device__ __forceinline__ float qgelu(float v) {
    // v * sigmoid(1.702 v) = v / (1 + exp(-1.702 v))
    return v / (1.0f + __expf(-1.702f * v));
}

__global__ __launch_bounds__(256) void convpass_fused(
    const float* __restrict__ x,
    const float* __restrict__ conv_w,
    const float* __restrict__ conv_b,
    const float* __restrict__ centers,
    const float* __restrict__ widths,
    const float* __restrict__ down_w,
    const float* __restrict__ down_b,
    float* __restrict__ out)
{
    const int g = blockIdx.x;   // group == token-1
    const int b = blockIdx.y;   // batch
    const int tid = threadIdx.x;        // 256 threads = one per pixel
    const int px = tid & 15;
    const int py = tid >> 4;

    __shared__ float s_in[3][256];   // input patch, 3 channels
    __shared__ float s_h[12][256];   // normalized histogram channels
    __shared__ float s_cw[81];       // conv weights for this group (3oc x 3ic x 3 x 3)
    __shared__ float s_dw[36];       // down_w for this group (3 x 12)
    __shared__ float s_cen[12];
    __shared__ float s_wid[12];
    __shared__ float s_cb[3];
    __shared__ float s_db[3];

    // ---- stage inputs & per-group params ----
    const float* xin = x + ((size_t)b * 197 + (size_t)(g + 1)) * 768;
    #pragma unroll
    for (int ic = 0; ic < 3; ++ic)
        s_in[ic][tid] = xin[ic * 256 + tid];

    if (tid < 81) {
        s_cw[tid] = conv_w[g * 81 + tid];
    } else if (tid < 117) {
        s_dw[tid - 81] = down_w[g * 36 + (tid - 81)];
    } else if (tid < 129) {
        s_cen[tid - 117] = centers[g * 12 + (tid - 117)];
    } else if (tid < 141) {
        s_wid[tid - 129] = widths[g * 12 + (tid - 129)];
    } else if (tid < 144) {
        s_cb[tid - 141] = conv_b[g * 3 + (tid - 141)];
    } else if (tid < 147) {
        s_db[tid - 144] = down_b[g * 3 + (tid - 144)];
    }
    __syncthreads();

    // ---- grouped 3x3 conv (pad=1) + quick_gelu ----
    float y[3];
    #pragma unroll
    for (int oc = 0; oc < 3; ++oc) {
        float acc = s_cb[oc];
        #pragma unroll
        for (int ic = 0; ic < 3; ++ic) {
            #pragma unroll
            for (int ky = 0; ky < 3; ++ky) {
                const int iy = py + ky - 1;
                #pragma unroll
                for (int kx = 0; kx < 3; ++kx) {
                    const int ix = px + kx - 1;
                    if (iy >= 0 && iy < 16 && ix >= 0 && ix < 16)
                        acc = fmaf(s_in[ic][iy * 16 + ix],
                                   s_cw[oc * 27 + ic * 9 + ky * 3 + kx], acc);
                }
            }
        }
        y[oc] = qgelu(acc);
    }

    // ---- 4-bin soft histogram, normalized over bins ----
    #pragma unroll
    for (int oc = 0; oc < 3; ++oc) {
        float hb[NUM_BINS];
        float sum = 0.0f;
        #pragma unroll
        for (int k = 0; k < NUM_BINS; ++k) {
            float v = fmaf(s_wid[oc * 4 + k], fabsf(y[oc] + s_cen[oc * 4 + k]), 1.0f);
            v = v > 0.0f ? v : 0.0f;   // relu
            hb[k] = v;
            sum += v;
        }
        const float inv = 1.0f / (sum + 1e-5f);
        #pragma unroll
        for (int k = 0; k < NUM_BINS; ++k)
            s_h[oc * 4 + k][tid] = hb[k] * inv;
    }
    __syncthreads();

    // ---- 3x3 avgpool (exclude pad) + quick_gelu + 12->3 down projection ----
    const int vx = 1 + (px > 0) + (px < 15);
    const int vy = 1 + (py > 0) + (py < 15);
    const float rcnt = 1.0f / (float)(vx * vy);

    float o[3] = {0.0f, 0.0f, 0.0f};
    #pragma unroll
    for (int i = 0; i < 12; ++i) {
        float s = 0.0f;
        #pragma unroll
        for (int dy = -1; dy <= 1; ++dy) {
            const int iy = py + dy;
            #pragma unroll
            for (int dx = -1; dx <= 1; ++dx) {
                const int ix = px + dx;
                if (iy >= 0 && iy < 16 && ix >= 0 && ix < 16)
                    s += s_h[i][iy * 16 + ix];
            }
        }
        const float p = qgelu(s * rcnt);
        #pragma unroll
        for (int o2 = 0; o2 < 3; ++o2)
            o[o2] = fmaf(p, s_dw[o2 * 12 + i], o[o2]);
    }

    float* outp = out + ((size_t)b * 197 + (size_t)(g + 1)) * 768;
    #pragma unroll
    for (int o2 = 0; o2 < 3; ++o2)
        outp[o2 * 256 + tid] = o[o2] + s_db[o2];
}

// copy the CLS token straight through
__global__ __launch_bounds__(256) void cls_copy(
    const float* __restrict__ x, float* __restrict__ out, int nB)
{
    const int i = blockIdx.x * 256 + threadIdx.x;  // nB * 768 elements
    if (i >= nB * 768) return;
    const int b = i / 768;
    const int f = i - b * 768;
    const size_t idx = (size_t)b * 197 * 768 + (size_t)f;
    out[idx] = x[idx];
}

extern "C" void kernel_launch(void* const* d_in, const int* in_sizes, int n_in,
                              void* d_out, int out_size, void* d_ws, size_t ws_size,
                              hipStream_t stream) {
    const float* x       = (const float*)d_in[0];
    const float* conv_w  = (const float*)d_in[1];
    const float* conv_b  = (const float*)d_in[2];
    const float* centers = (const float*)d_in[3];
    const float* widths  = (const float*)d_in[4];
    const float* down_w  = (const float*)d_in[5];
    const float* down_b  = (const float*)d_in[6];
    float* out = (float*)d_out;

    const int B = in_sizes[0] / (197 * 768);

    dim3 grid(GROUPS, B);
    convpass_fused<<<grid, 256, 0, stream>>>(x, conv_w, conv_b, centers, widths,
                                             down_w, down_b, out);

    const int ncls = B * 768;
    cls_copy<<<(ncls + 255) / 256, 256, 0, stream>>>(x, out, B);
}

// Round 2
// 44.717 us; speedup vs baseline: 1.8742x; 1.8742x over previous
//
#include <hip/hip_runtime.h>

#define GROUPS 196

__device__ __forceinline__ float qgelu(float v) {
    // v * sigmoid(1.702 v) = v / (1 + exp(-1.702 v))
    return v * __builtin_amdgcn_rcpf(1.0f + __expf(-1.702f * v));
}

__global__ __launch_bounds__(256) void convpass_fused(
    const float* __restrict__ x,
    const float* __restrict__ conv_w,
    const float* __restrict__ conv_b,
    const float* __restrict__ centers,
    const float* __restrict__ widths,
    const float* __restrict__ down_w,
    const float* __restrict__ down_b,
    float* __restrict__ out)
{
    const int g = blockIdx.x;   // group == token-1 (wave-uniform -> s_loads for params)
    const int b = blockIdx.y;   // batch
    const int tid = threadIdx.x;
    const int px = tid & 15;
    const int py = tid >> 4;
    const int P = (py + 1) * 18 + (px + 1);   // interior pixel in 18x18 halo frame

    __shared__ float4 s_in4[324];      // [18*18] -> {c0,c1,c2,pad}
    __shared__ float4 s_h4[324 * 3];   // [18*18] -> 12 hist channels (3x float4)

    // ---- zero the 68-pixel halo ring (valid zero-pad for conv AND pool) ----
    if (tid < 68) {
        int j = tid, pix;
        if (j < 18)      pix = j;                    // top row
        else if (j < 36) pix = 17 * 18 + (j - 18);   // bottom row
        else if (j < 52) pix = (j - 36 + 1) * 18;    // left col
        else             pix = (j - 52 + 1) * 18 + 17; // right col
        const float4 z = make_float4(0.f, 0.f, 0.f, 0.f);
        s_in4[pix] = z;
        s_h4[pix * 3 + 0] = z;
        s_h4[pix * 3 + 1] = z;
        s_h4[pix * 3 + 2] = z;
    }

    // ---- stage input patch (coalesced global reads, pixel-major LDS) ----
    const float* xin = x + ((size_t)b * 197 + (size_t)(g + 1)) * 768;
    s_in4[P] = make_float4(xin[tid], xin[256 + tid], xin[512 + tid], 0.f);

    __syncthreads();

    // ---- grouped 3x3 conv (zero pad via halo) + quick_gelu ----
    const float* cw = conv_w + g * 81;   // uniform -> SGPR
    float y0 = conv_b[g * 3 + 0];
    float y1 = conv_b[g * 3 + 1];
    float y2 = conv_b[g * 3 + 2];
    #pragma unroll
    for (int ky = 0; ky < 3; ++ky) {
        #pragma unroll
        for (int kx = 0; kx < 3; ++kx) {
            const int kk = ky * 3 + kx;
            const float4 v = s_in4[P + (ky - 1) * 18 + (kx - 1)];
            y0 = fmaf(v.x, cw[     kk], fmaf(v.y, cw[ 9 + kk], fmaf(v.z, cw[18 + kk], y0)));
            y1 = fmaf(v.x, cw[27 + kk], fmaf(v.y, cw[36 + kk], fmaf(v.z, cw[45 + kk], y1)));
            y2 = fmaf(v.x, cw[54 + kk], fmaf(v.y, cw[63 + kk], fmaf(v.z, cw[72 + kk], y2)));
        }
    }
    const float yq0 = qgelu(y0);
    const float yq1 = qgelu(y1);
    const float yq2 = qgelu(y2);
    const float yq[3] = {yq0, yq1, yq2};

    // ---- 4-bin soft histogram, normalized over bins ----
    const float* cen = centers + g * 12;  // uniform -> SGPR
    const float* wid = widths + g * 12;
    #pragma unroll
    for (int oc = 0; oc < 3; ++oc) {
        float t0 = fmaxf(fmaf(wid[oc*4+0], fabsf(yq[oc] + cen[oc*4+0]), 1.0f), 0.f);
        float t1 = fmaxf(fmaf(wid[oc*4+1], fabsf(yq[oc] + cen[oc*4+1]), 1.0f), 0.f);
        float t2 = fmaxf(fmaf(wid[oc*4+2], fabsf(yq[oc] + cen[oc*4+2]), 1.0f), 0.f);
        float t3 = fmaxf(fmaf(wid[oc*4+3], fabsf(yq[oc] + cen[oc*4+3]), 1.0f), 0.f);
        const float inv = __builtin_amdgcn_rcpf(t0 + t1 + t2 + t3 + 1e-5f);
        s_h4[P * 3 + oc] = make_float4(t0 * inv, t1 * inv, t2 * inv, t3 * inv);
    }

    __syncthreads();

    // ---- 3x3 avgpool (exclude pad) : unconditional halo reads ----
    float s[12] = {0.f, 0.f, 0.f, 0.f, 0.f, 0.f, 0.f, 0.f, 0.f, 0.f, 0.f, 0.f};
    #pragma unroll
    for (int dy = -1; dy <= 1; ++dy) {
        #pragma unroll
        for (int dx = -1; dx <= 1; ++dx) {
            const int np = (P + dy * 18 + dx) * 3;
            const float4 a = s_h4[np + 0];
            const float4 c = s_h4[np + 1];
            const float4 d = s_h4[np + 2];
            s[0] += a.x; s[1]  += a.y; s[2]  += a.z; s[3]  += a.w;
            s[4] += c.x; s[5]  += c.y; s[6]  += c.z; s[7]  += c.w;
            s[8] += d.x; s[9]  += d.y; s[10] += d.z; s[11] += d.w;
        }
    }

    const int vx = 1 + (px > 0) + (px < 15);
    const int vy = 1 + (py > 0) + (py < 15);
    const float rcnt = __builtin_amdgcn_rcpf((float)(vx * vy));

    // ---- quick_gelu + 12->3 down projection ----
    const float* dwp = down_w + g * 36;   // uniform -> SGPR
    float o0 = down_b[g * 3 + 0];
    float o1 = down_b[g * 3 + 1];
    float o2 = down_b[g * 3 + 2];
    #pragma unroll
    for (int i = 0; i < 12; ++i) {
        const float p = qgelu(s[i] * rcnt);
        o0 = fmaf(p, dwp[i],      o0);
        o1 = fmaf(p, dwp[12 + i], o1);
        o2 = fmaf(p, dwp[24 + i], o2);
    }

    float* outp = out + ((size_t)b * 197 + (size_t)(g + 1)) * 768;
    outp[tid]       = o0;
    outp[256 + tid] = o1;
    outp[512 + tid] = o2;

    // ---- fold CLS pass-through into g==0 blocks ----
    if (g == 0) {
        const float* xc = x + (size_t)b * 197 * 768;
        float* oc_ = out + (size_t)b * 197 * 768;
        oc_[tid]       = xc[tid];
        oc_[256 + tid] = xc[256 + tid];
        oc_[512 + tid] = xc[512 + tid];
    }
}

extern "C" void kernel_launch(void* const* d_in, const int* in_sizes, int n_in,
                              void* d_out, int out_size, void* d_ws, size_t ws_size,
                              hipStream_t stream) {
    const float* x       = (const float*)d_in[0];
    const float* conv_w  = (const float*)d_in[1];
    const float* conv_b  = (const float*)d_in[2];
    const float* centers = (const float*)d_in[3];
    const float* widths  = (const float*)d_in[4];
    const float* down_w  = (const float*)d_in[5];
    const float* down_b  = (const float*)d_in[6];
    float* out = (float*)d_out;

    const int B = in_sizes[0] / (197 * 768);

    dim3 grid(GROUPS, B);
    convpass_fused<<<grid, 256, 0, stream>>>(x, conv_w, conv_b, centers, widths,
                                             down_w, down_b, out);
}

// Round 3
// 38.743 us; speedup vs baseline: 2.1631x; 1.1542x over previous
//
#include <hip/hip_runtime.h>

#define GROUPS 196

__device__ __forceinline__ float qgelu(float v) {
    // v * sigmoid(1.702 v) = v / (1 + exp(-1.702 v))
    return v * __builtin_amdgcn_rcpf(1.0f + __expf(-1.702f * v));
}

// DPP row helpers. A pixel row (16 px) == one DPP row (16 lanes).
// left  = value of px-1 (row_shr:1), zero at px==0  (bound_ctrl)
// right = value of px+1 (row_shl:1), zero at px==15 (bound_ctrl)
__device__ __forceinline__ float dpp_left(float v) {
    return __int_as_float(__builtin_amdgcn_update_dpp(
        0, __float_as_int(v), 0x111, 0xF, 0xF, true));
}
__device__ __forceinline__ float dpp_right(float v) {
    return __int_as_float(__builtin_amdgcn_update_dpp(
        0, __float_as_int(v), 0x101, 0xF, 0xF, true));
}

__global__ __launch_bounds__(256) void convpass_fused(
    const float* __restrict__ x,
    const float* __restrict__ conv_w,
    const float* __restrict__ conv_b,
    const float* __restrict__ centers,
    const float* __restrict__ widths,
    const float* __restrict__ down_w,
    const float* __restrict__ down_b,
    float* __restrict__ out)
{
    const int g = blockIdx.x;   // group == token-1 (wave-uniform -> s_loads)
    const int b = blockIdx.y;   // batch
    const int tid = threadIdx.x;
    const int px = tid & 15;
    const int py = tid >> 4;
    const int ip = (py + 1) * 16 + px;   // interior row in 18-row halo frame

    __shared__ float4 s_in[288];      // [18 rows][16 px] {c0,c1,c2,_}, rows 0/17 zero
    __shared__ float4 s_rs[3][288];   // horizontal row-sums of 12 hist channels

    // ---- zero top/bottom halo rows (32 pixels) of all planes ----
    if (tid < 32) {
        const int pix = (tid < 16) ? tid : (272 + (tid - 16));  // row 0 / row 17
        const float4 z = make_float4(0.f, 0.f, 0.f, 0.f);
        s_in[pix] = z;
        s_rs[0][pix] = z;
        s_rs[1][pix] = z;
        s_rs[2][pix] = z;
    }

    // ---- stage input patch (coalesced) ----
    const float* xin = x + ((size_t)b * 197 + (size_t)(g + 1)) * 768;
    s_in[ip] = make_float4(xin[tid], xin[256 + tid], xin[512 + tid], 0.f);

    __syncthreads();

    // ---- grouped 3x3 conv: 3 vertical LDS reads, horizontal via DPP ----
    const float* cw = conv_w + g * 81;   // uniform -> scalar loads
    float yy[3] = { conv_b[g * 3 + 0], conv_b[g * 3 + 1], conv_b[g * 3 + 2] };

    const int vbase = py * 16 + px;      // row (py+1)-1 in halo frame
    float4 vrow[3];
    vrow[0] = s_in[vbase];           // py-1
    vrow[1] = s_in[vbase + 16];      // py
    vrow[2] = s_in[vbase + 32];      // py+1

    #pragma unroll
    for (int ky = 0; ky < 3; ++ky) {
        const float c0 = vrow[ky].x, c1 = vrow[ky].y, c2 = vrow[ky].z;
        const float l0 = dpp_left(c0),  l1 = dpp_left(c1),  l2 = dpp_left(c2);
        const float r0 = dpp_right(c0), r1 = dpp_right(c1), r2 = dpp_right(c2);
        #pragma unroll
        for (int oc = 0; oc < 3; ++oc) {
            const float* w = cw + oc * 27 + ky * 3;  // + ic*9 + kx
            float a = yy[oc];
            a = fmaf(l0, w[0],      a);   // ic0: kx=0 multiplies px-1
            a = fmaf(c0, w[1],      a);
            a = fmaf(r0, w[2],      a);
            a = fmaf(l1, w[9 + 0],  a);
            a = fmaf(c1, w[9 + 1],  a);
            a = fmaf(r1, w[9 + 2],  a);
            a = fmaf(l2, w[18 + 0], a);
            a = fmaf(c2, w[18 + 1], a);
            a = fmaf(r2, w[18 + 2], a);
            yy[oc] = a;
        }
    }

    // ---- quick_gelu + 4-bin soft histogram + horizontal 3-sum (DPP) ----
    const float* cen = centers + g * 12;
    const float* wid = widths  + g * 12;
    float rs[12];
    #pragma unroll
    for (int oc = 0; oc < 3; ++oc) {
        const float yv = qgelu(yy[oc]);
        float t0 = fmaxf(fmaf(wid[oc*4+0], fabsf(yv + cen[oc*4+0]), 1.0f), 0.f);
        float t1 = fmaxf(fmaf(wid[oc*4+1], fabsf(yv + cen[oc*4+1]), 1.0f), 0.f);
        float t2 = fmaxf(fmaf(wid[oc*4+2], fabsf(yv + cen[oc*4+2]), 1.0f), 0.f);
        float t3 = fmaxf(fmaf(wid[oc*4+3], fabsf(yv + cen[oc*4+3]), 1.0f), 0.f);
        const float inv = __builtin_amdgcn_rcpf(t0 + t1 + t2 + t3 + 1e-5f);
        #pragma unroll
        for (int k = 0; k < 4; ++k) {
            const float tk = (k == 0 ? t0 : k == 1 ? t1 : k == 2 ? t2 : t3);
            const float h = tk * inv;
            rs[oc * 4 + k] = h + dpp_left(h) + dpp_right(h);
        }
    }

    s_rs[0][ip] = make_float4(rs[0], rs[1], rs[2],  rs[3]);
    s_rs[1][ip] = make_float4(rs[4], rs[5], rs[6],  rs[7]);
    s_rs[2][ip] = make_float4(rs[8], rs[9], rs[10], rs[11]);

    __syncthreads();

    // ---- vertical 3-sum + exclude-pad scale + quick_gelu + 12->3 down proj ----
    const int vx = 1 + (px > 0) + (px < 15);
    const int vy = 1 + (py > 0) + (py < 15);
    const float rcnt = __builtin_amdgcn_rcpf((float)(vx * vy));

    const float* dwp = down_w + g * 36;
    float o0 = down_b[g * 3 + 0];
    float o1 = down_b[g * 3 + 1];
    float o2 = down_b[g * 3 + 2];

    #pragma unroll
    for (int p = 0; p < 3; ++p) {
        const float4 up = s_rs[p][ip - 16];
        const float4 dn = s_rs[p][ip + 16];
        const float ps[4] = {
            (rs[p*4+0] + up.x + dn.x) * rcnt,
            (rs[p*4+1] + up.y + dn.y) * rcnt,
            (rs[p*4+2] + up.z + dn.z) * rcnt,
            (rs[p*4+3] + up.w + dn.w) * rcnt
        };
        #pragma unroll
        for (int k = 0; k < 4; ++k) {
            const float q = qgelu(ps[k]);
            const int i = p * 4 + k;
            o0 = fmaf(q, dwp[i],      o0);
            o1 = fmaf(q, dwp[12 + i], o1);
            o2 = fmaf(q, dwp[24 + i], o2);
        }
    }

    float* outp = out + ((size_t)b * 197 + (size_t)(g + 1)) * 768;
    outp[tid]       = o0;
    outp[256 + tid] = o1;
    outp[512 + tid] = o2;

    // ---- CLS pass-through folded into g==0 blocks ----
    if (g == 0) {
        const float* xc = x + (size_t)b * 197 * 768;
        float* ocp = out + (size_t)b * 197 * 768;
        ocp[tid]       = xc[tid];
        ocp[256 + tid] = xc[256 + tid];
        ocp[512 + tid] = xc[512 + tid];
    }
}

extern "C" void kernel_launch(void* const* d_in, const int* in_sizes, int n_in,
                              void* d_out, int out_size, void* d_ws, size_t ws_size,
                              hipStream_t stream) {
    const float* x       = (const float*)d_in[0];
    const float* conv_w  = (const float*)d_in[1];
    const float* conv_b  = (const float*)d_in[2];
    const float* centers = (const float*)d_in[3];
    const float* widths  = (const float*)d_in[4];
    const float* down_w  = (const float*)d_in[5];
    const float* down_b  = (const float*)d_in[6];
    float* out = (float*)d_out;

    const int B = in_sizes[0] / (197 * 768);

    dim3 grid(GROUPS, B);
    convpass_fused<<<grid, 256, 0, stream>>>(x, conv_w, conv_b, centers, widths,
                                             down_w, down_b, out);
}